// Round 2
// baseline (1044.084 us; speedup 1.0000x reference)
//
#include <hip/hip_runtime.h>
#include <hip/hip_bf16.h>
#include <cstddef>

#define DD   128
#define PP   8192
#define KK   8
#define NN   131072
#define NE   65536
#define NLVL 15
#define AST  136   // A-stage row stride in bf16 elements (+8 pad -> 272B, 2-way banks only)

typedef __bf16 bf16x8 __attribute__((ext_vector_type(8)));
typedef float  f32x4  __attribute__((ext_vector_type(4)));

__device__ __forceinline__ float bf_lo(unsigned u) { return __uint_as_float(u << 16); }
__device__ __forceinline__ float bf_hi(unsigned u) { return __uint_as_float(u & 0xffff0000u); }

// ---------------- weight pre-pack: fp32 [k][n] -> bf16 MFMA B-fragment order ----------------
// frag element j of lane l for (ct,ks) tile: W[ks*32 + (l>>4)*8 + j][ct*16 + (l&15)]
// packed index: ((ct*4+ks)*64 + lane)*8 + j
__global__ __launch_bounds__(256) void pack_w(
    const float* w0, const float* w1, const float* w2,
    const float* w3, const float* w4, const float* w5,
    __bf16* dst) {
  const float* ws[6] = {w0, w1, w2, w3, w4, w5};
  const float* w = ws[blockIdx.x];
  __bf16* o = dst + blockIdx.x * 16384;
  for (int t = 0; t < 64; t++) {
    int i = t * 256 + threadIdx.x;
    int j = i & 7, f = i >> 3;
    int lane = f & 63, ctks = f >> 6;
    int ks = ctks & 3, ct = ctks >> 2;
    int k = ks * 32 + ((lane >> 4) << 3) + j;
    int n = (ct << 4) + (lane & 15);
    o[i] = (__bf16)w[k * 128 + n];
  }
}

// ---------------- 16-row x 128-col x 128-k MFMA GEMM per wave ----------------
// Arow: A-stage base for this wave's 16 rows (bf16, stride AST)
// wbuf: packed B fragments (16384 bf16)
__device__ __forceinline__ void gemm128(const __bf16* __restrict__ Arow,
                                        const __bf16* __restrict__ wbuf,
                                        int lane, f32x4 acc[8]) {
  int quad = lane >> 4, m = lane & 15;
  bf16x8 a[4];
#pragma unroll
  for (int ks = 0; ks < 4; ks++)
    a[ks] = *(const bf16x8*)(Arow + m * AST + ks * 32 + quad * 8);
#pragma unroll
  for (int ct = 0; ct < 8; ct++) {
#pragma unroll
    for (int ks = 0; ks < 4; ks++) {
      bf16x8 b = *(const bf16x8*)(wbuf + ((ct * 4 + ks) * 64 + lane) * 8);
      acc[ct] = __builtin_amdgcn_mfma_f32_16x16x32_bf16(a[ks], b, acc[ct], 0, 0, 0);
    }
  }
}

// ---------------- node transform: h = relu(x@w1+b1)@w2 + b2 (fp32 out) ----------------
__global__ __launch_bounds__(256) void nt_kernel(
    const float* __restrict__ x,
    const __bf16* __restrict__ w1p, const float* __restrict__ b1,
    const __bf16* __restrict__ w2p, const float* __restrict__ b2,
    float* __restrict__ h) {
  __shared__ __bf16 wbuf[16384];
  __shared__ __bf16 Ast[64 * AST];
  int tid = threadIdx.x;
  size_t base = (size_t)blockIdx.x * 64;

  {
    const float4* s4 = (const float4*)w1p;
    float4* d4 = (float4*)wbuf;
#pragma unroll
    for (int i = 0; i < 8; i++) d4[tid + i * 256] = s4[tid + i * 256];
  }
  const float4* xs = (const float4*)(x + base * 128);
#pragma unroll
  for (int i = 0; i < 8; i++) {
    int idx = tid + i * 256;            // 0..2047 float4s = 64 rows x 128
    float4 v = xs[idx];
    int r = idx >> 5, c = (idx & 31) * 4;
    union { __bf16 b[4]; uint2 u; } pk;
    pk.b[0] = (__bf16)v.x; pk.b[1] = (__bf16)v.y;
    pk.b[2] = (__bf16)v.z; pk.b[3] = (__bf16)v.w;
    *(uint2*)(Ast + r * AST + c) = pk.u;
  }
  __syncthreads();

  int lane = tid & 63, wv = tid >> 6, quad = lane >> 4, c16 = lane & 15;
  f32x4 acc[8];
#pragma unroll
  for (int ct = 0; ct < 8; ct++) acc[ct] = (f32x4){0.f, 0.f, 0.f, 0.f};
  gemm128(Ast + wv * 16 * AST, wbuf, lane, acc);
  // relu+bias -> A-stage (own rows only; no cross-wave hazard)
#pragma unroll
  for (int ct = 0; ct < 8; ct++) {
    int col = ct * 16 + c16;
    float bias = b1[col];
#pragma unroll
    for (int rg = 0; rg < 4; rg++) {
      int rloc = wv * 16 + quad * 4 + rg;
      Ast[rloc * AST + col] = (__bf16)fmaxf(acc[ct][rg] + bias, 0.f);
    }
  }
  __syncthreads();
  {
    const float4* s4 = (const float4*)w2p;
    float4* d4 = (float4*)wbuf;
#pragma unroll
    for (int i = 0; i < 8; i++) d4[tid + i * 256] = s4[tid + i * 256];
  }
  __syncthreads();
#pragma unroll
  for (int ct = 0; ct < 8; ct++) acc[ct] = (f32x4){0.f, 0.f, 0.f, 0.f};
  gemm128(Ast + wv * 16 * AST, wbuf, lane, acc);
#pragma unroll
  for (int ct = 0; ct < 8; ct++) {
    int col = ct * 16 + c16;
    float bias = b2[col];
#pragma unroll
    for (int rg = 0; rg < 4; rg++) {
      size_t n = base + wv * 16 + quad * 4 + rg;
      h[n * 128 + col] = acc[ct][rg] + bias;
    }
  }
}

// ---------------- CSR build (reverse-edge transpose) ----------------
__global__ __launch_bounds__(256) void csr_count(const int* __restrict__ src_all,
                                                 int* __restrict__ deg) {
  int e = blockIdx.x * 256 + threadIdx.x;
  int l = e >> 16;
  int q = src_all[e];
  atomicAdd(&deg[l * PP + q], 1);
}

__global__ __launch_bounds__(256) void csr_scan(const int* __restrict__ deg,
                                                int* __restrict__ offs,
                                                int* __restrict__ cursor) {
  int l = blockIdx.x;
  int t = threadIdx.x;
  const int* d = deg + l * PP;
  __shared__ int ssum[256];
  int loc[32];
  int s = 0;
#pragma unroll
  for (int j = 0; j < 32; j++) { loc[j] = d[t * 32 + j]; s += loc[j]; }
  ssum[t] = s;
  __syncthreads();
  for (int off = 1; off < 256; off <<= 1) {
    int v = (t >= off) ? ssum[t - off] : 0;
    __syncthreads();
    ssum[t] += v;
    __syncthreads();
  }
  int run = (t == 0) ? 0 : ssum[t - 1];
#pragma unroll
  for (int j = 0; j < 32; j++) {
    offs[l * (PP + 1) + t * 32 + j] = run;
    cursor[l * PP + t * 32 + j] = run;
    run += loc[j];
  }
  if (t == 255) offs[l * (PP + 1) + PP] = run;
}

__global__ __launch_bounds__(256) void csr_fill(const int* __restrict__ src_all,
                                                int* __restrict__ cursor,
                                                int* __restrict__ edges) {
  int e = blockIdx.x * 256 + threadIdx.x;
  int l = e >> 16;
  int q = src_all[e];
  int pos = atomicAdd(&cursor[l * PP + q], 1);
  edges[l * NE + pos] = (e & (NE - 1)) >> 3;
}

// ---------------- fused message-passing step ----------------
// grid = 256: blocks 0..127 = forward level `step`, 128..255 = reverse level 15-step
// block = 256 threads = 4 waves, 64 rows/block (16 rows/wave)
__global__ __launch_bounds__(256) void mp_step(
    const float* __restrict__ h,
    const int* __restrict__ src_all,
    const int* __restrict__ offs,
    const int* __restrict__ edges,
    const __bf16* __restrict__ wpk,  // [0]=f_upd [1]=f_pre [2]=b_upd [3]=b_pre
    const float* __restrict__ f_upd_b, const float* __restrict__ f_pre_b,
    const float* __restrict__ b_upd_b, const float* __restrict__ b_pre_b,
    const __bf16* __restrict__ mf_in, __bf16* __restrict__ mf_out,
    const __bf16* __restrict__ mb_in, __bf16* __restrict__ mb_out,
    float* __restrict__ out, int step) {
  __shared__ __bf16 wbuf[16384];
  __shared__ __bf16 Ast[64 * AST];
  __shared__ int eLDS[512];
  int tid = threadIdx.x;
  bool is_fwd = blockIdx.x < 128;
  int tile = (blockIdx.x & 127) * 64;
  int level = is_fwd ? step : 15 - step;
  const __bf16* updw = wpk + (is_fwd ? 0 : 2) * 16384;
  const __bf16* prew = wpk + (is_fwd ? 1 : 3) * 16384;
  const float* updb = is_fwd ? f_upd_b : b_upd_b;
  const float* preb = is_fwd ? f_pre_b : b_pre_b;
  const __bf16* m_in = is_fwd ? mf_in : mb_in;
  __bf16* m_out = is_fwd ? mf_out : mb_out;
  int col_off = is_fwd ? 0 : 128;

  {
    const float4* s4 = (const float4*)updw;
    float4* d4 = (float4*)wbuf;
#pragma unroll
    for (int i = 0; i < 8; i++) d4[tid + i * 256] = s4[tid + i * 256];
  }
  if (is_fwd && step > 0) {
    const int* sl = src_all + (step - 1) * NE + tile * 8;
    eLDS[tid] = sl[tid];
    eLDS[tid + 256] = sl[tid + 256];
  }
  __syncthreads();

  // ---- gather z -> A-stage (bf16) ----
  int c32 = tid & 31, r0 = tid >> 5;
  if (step > 0) {
    if (is_fwd) {
#pragma unroll
      for (int pass = 0; pass < 8; pass++) {
        int r = pass * 8 + r0;
        float a0 = 0.f, a1 = 0.f, a2 = 0.f, a3 = 0.f;
#pragma unroll
        for (int k = 0; k < 8; k++) {
          int s = eLDS[r * 8 + k];
          uint2 raw = *(const uint2*)(m_in + s * 128 + c32 * 4);
          a0 += bf_lo(raw.x); a1 += bf_hi(raw.x);
          a2 += bf_lo(raw.y); a3 += bf_hi(raw.y);
        }
        union { __bf16 b[4]; uint2 u; } pk;
        pk.b[0] = (__bf16)(a0 * 0.125f); pk.b[1] = (__bf16)(a1 * 0.125f);
        pk.b[2] = (__bf16)(a2 * 0.125f); pk.b[3] = (__bf16)(a3 * 0.125f);
        *(uint2*)(Ast + r * AST + c32 * 4) = pk.u;
      }
    } else {
      const int* off_l = offs + level * (PP + 1);
      const int* ep = edges + level * NE;
#pragma unroll
      for (int pass = 0; pass < 8; pass++) {
        int r = pass * 8 + r0;
        int q = tile + r;
        int lo = off_l[q], hi = off_l[q + 1];
        float a0 = 0.f, a1 = 0.f, a2 = 0.f, a3 = 0.f;
        for (int idx = lo; idx < hi; idx++) {
          int p = ep[idx];
          uint2 raw = *(const uint2*)(m_in + p * 128 + c32 * 4);
          a0 += bf_lo(raw.x); a1 += bf_hi(raw.x);
          a2 += bf_lo(raw.y); a3 += bf_hi(raw.y);
        }
        float inv = (hi > lo) ? 1.f / (float)(hi - lo) : 0.f;
        union { __bf16 b[4]; uint2 u; } pk;
        pk.b[0] = (__bf16)(a0 * inv); pk.b[1] = (__bf16)(a1 * inv);
        pk.b[2] = (__bf16)(a2 * inv); pk.b[3] = (__bf16)(a3 * inv);
        *(uint2*)(Ast + r * AST + c32 * 4) = pk.u;
      }
    }
  } else {
    uint2 z = {0u, 0u};
#pragma unroll
    for (int pass = 0; pass < 8; pass++)
      *(uint2*)(Ast + (pass * 8 + r0) * AST + c32 * 4) = z;
  }
  __syncthreads();

  // ---- GEMM1: u = relu(z@upd_w + upd_b) + h ; write out half; u -> A-stage ----
  int lane = tid & 63, wv = tid >> 6, quad = lane >> 4, c16 = lane & 15;
  f32x4 acc[8];
#pragma unroll
  for (int ct = 0; ct < 8; ct++) acc[ct] = (f32x4){0.f, 0.f, 0.f, 0.f};
  gemm128(Ast + wv * 16 * AST, wbuf, lane, acc);

  size_t nbase = (size_t)(level * PP + tile);
#pragma unroll
  for (int ct = 0; ct < 8; ct++) {
    int col = ct * 16 + c16;
    float bias = updb[col];
#pragma unroll
    for (int rg = 0; rg < 4; rg++) {
      int rloc = wv * 16 + quad * 4 + rg;
      size_t n = nbase + rloc;
      float v = fmaxf(acc[ct][rg] + bias, 0.f) + h[n * 128 + col];
      out[n * 256 + col_off + col] = v;
      Ast[rloc * AST + col] = (__bf16)v;
    }
  }
  __syncthreads();

  // ---- GEMM2: m_out = relu(u @ pre_w + pre_b) ----
  if (step < 15) {
    {
      const float4* s4 = (const float4*)prew;
      float4* d4 = (float4*)wbuf;
#pragma unroll
      for (int i = 0; i < 8; i++) d4[tid + i * 256] = s4[tid + i * 256];
    }
    __syncthreads();
#pragma unroll
    for (int ct = 0; ct < 8; ct++) acc[ct] = (f32x4){0.f, 0.f, 0.f, 0.f};
    gemm128(Ast + wv * 16 * AST, wbuf, lane, acc);
#pragma unroll
    for (int ct = 0; ct < 8; ct++) {
      int col = ct * 16 + c16;
      float bias = preb[col];
#pragma unroll
      for (int rg = 0; rg < 4; rg++) {
        int rloc = wv * 16 + quad * 4 + rg;
        float m = fmaxf(acc[ct][rg] + bias, 0.f);
        m_out[(size_t)(tile + rloc) * 128 + col] = (__bf16)m;
      }
    }
  }
}

extern "C" void kernel_launch(void* const* d_in, const int* in_sizes, int n_in,
                              void* d_out, int out_size, void* d_ws, size_t ws_size,
                              hipStream_t stream) {
  const float* x       = (const float*)d_in[0];
  const int*   src     = (const int*)d_in[1];
  const float* nt_w1   = (const float*)d_in[2];
  const float* nt_b1   = (const float*)d_in[3];
  const float* nt_w2   = (const float*)d_in[4];
  const float* nt_b2   = (const float*)d_in[5];
  const float* f_pre_w = (const float*)d_in[6];
  const float* f_pre_b = (const float*)d_in[7];
  const float* f_upd_w = (const float*)d_in[8];
  const float* f_upd_b = (const float*)d_in[9];
  const float* b_pre_w = (const float*)d_in[10];
  const float* b_pre_b = (const float*)d_in[11];
  const float* b_upd_w = (const float*)d_in[12];
  const float* b_upd_b = (const float*)d_in[13];
  float* out = (float*)d_out;

  char* wsb = (char*)d_ws;
  float* h    = (float*)wsb;                                  // 64 MB
  __bf16* mf0 = (__bf16*)(wsb + (size_t)NN * 128 * 4);        // 2 MB each
  __bf16* mf1 = mf0 + (size_t)PP * 128;
  __bf16* mb0 = mf1 + (size_t)PP * 128;
  __bf16* mb1 = mb0 + (size_t)PP * 128;
  __bf16* wpk = mb1 + (size_t)PP * 128;                       // 6 x 32 KB packed
  int* deg    = (int*)(wpk + 6 * 16384);
  int* offs   = deg + NLVL * PP;
  int* cursor = offs + NLVL * (PP + 1);
  int* edges  = cursor + NLVL * PP;

  // pack order: [0]=nt_w1 [1]=nt_w2 [2]=f_upd [3]=f_pre [4]=b_upd [5]=b_pre
  pack_w<<<6, 256, 0, stream>>>(nt_w1, nt_w2, f_upd_w, f_pre_w, b_upd_w, b_pre_w, wpk);
  hipMemsetAsync(deg, 0, (size_t)NLVL * PP * sizeof(int), stream);
  csr_count<<<NLVL * NE / 256, 256, 0, stream>>>(src, deg);
  csr_scan<<<NLVL, 256, 0, stream>>>(deg, offs, cursor);
  csr_fill<<<NLVL * NE / 256, 256, 0, stream>>>(src, cursor, edges);
  nt_kernel<<<NN / 64, 256, 0, stream>>>(x, wpk, nt_b1, wpk + 16384, nt_b2, h);

  const __bf16* wmp = wpk + 2 * 16384;
  for (int s = 0; s < 16; s++) {
    const __bf16* mf_in = (s & 1) ? mf0 : mf1;
    __bf16* mf_out      = (s & 1) ? mf1 : mf0;
    const __bf16* mb_in = (s & 1) ? mb0 : mb1;
    __bf16* mb_out      = (s & 1) ? mb1 : mb0;
    mp_step<<<256, 256, 0, stream>>>(h, src, offs, edges, wmp,
                                     f_upd_b, f_pre_b, b_upd_b, b_pre_b,
                                     mf_in, mf_out, mb_in, mb_out, out, s);
  }
}